// Round 1
// baseline (139.823 us; speedup 1.0000x reference)
//
#include <hip/hip_runtime.h>
#include <math.h>

#define Ee 100
#define Hh 64
#define Bb 64
#define Tt 20
#define Kk 50

// ---------- helpers ----------
__device__ __forceinline__ float wave_sum(float v) {
    for (int m = 32; m >= 1; m >>= 1) v += __shfl_xor(v, m, 64);
    return v;
}
__device__ __forceinline__ float wave_max(float v) {
    for (int m = 32; m >= 1; m >>= 1) v = fmaxf(v, __shfl_xor(v, m, 64));
    return v;
}

// ---------- kernel 1: fused Q-network + prior (p_l - q_l) ----------
// rows: 5 segments of B*K (alpha,rho,lam,beta,mu_tab via itemset) + theta,gamma via userid
__global__ __launch_bounds__(256) void k_qprior(
    const float* __restrict__ alpha, const float* __restrict__ rho,
    const float* __restrict__ lam,   const float* __restrict__ beta,
    const float* __restrict__ mu_tab,const float* __restrict__ theta,
    const float* __restrict__ gamma_,const float* __restrict__ w1,
    const float* __restrict__ b1,    const float* __restrict__ w2,
    const float* __restrict__ b2,    const float* __restrict__ sigma_list,
    const int* __restrict__ itemset, const int* __restrict__ userid,
    float* __restrict__ partial)
{
    __shared__ float w1t[Ee * Hh];   // transposed: [e][j] -> conflict-free lane reads
    __shared__ float red[4];
    for (int i = threadIdx.x; i < Ee * Hh; i += 256) {
        int j = i / Ee, e = i - j * Ee;
        w1t[e * Hh + j] = w1[i];
    }
    __syncthreads();

    const int lane = threadIdx.x & 63;
    const float w2j = w2[lane];
    const float b1j = b1[lane];
    const float b2v = b2[0];

    const int wave   = (blockIdx.x * 256 + threadIdx.x) >> 6;
    const int nwaves = (gridDim.x * 256) >> 6;
    const int NROWS  = 5 * Bb * Kk + 2 * Bb;

    float acc = 0.f;
    for (int row = wave; row < NROWS; row += nwaves) {
        const float* tab; int idx; float coef;
        if (row < 5 * Bb * Kk) {
            int seg = row / (Bb * Kk);
            int r   = row - seg * (Bb * Kk);
            idx = itemset[r];
            tab = (seg == 0) ? alpha : (seg == 1) ? rho : (seg == 2) ? lam
                 : (seg == 3) ? beta : mu_tab;
            coef = -0.5f / sigma_list[seg];
        } else {
            int r = row - 5 * Bb * Kk;
            if (r < Bb) { tab = theta;  idx = userid[r];      coef = -0.5f / sigma_list[5]; }
            else        { tab = gamma_; idx = userid[r - Bb]; coef = -0.5f / sigma_list[6]; }
        }
        const float* x = tab + (long)idx * Ee;
        float h = b1j, ss = 0.f;
        #pragma unroll 4
        for (int e = 0; e < Ee; ++e) {
            float xe = x[e];
            h  = fmaf(xe, w1t[e * Hh + lane], h);
            ss = fmaf(xe, xe, ss);
        }
        float z = wave_sum(fmaxf(h, 0.f) * w2j) + b2v;
        float q = 1.f / (1.f + expf(-z));
        acc += coef * ss - q;     // identical on all lanes
    }

    int wid = threadIdx.x >> 6;
    if (lane == 0) red[wid] = acc;
    __syncthreads();
    if (threadIdx.x == 0) partial[blockIdx.x] = red[0] + red[1] + red[2] + red[3];
}

// ---------- kernel 2: per-b precompute ----------
// A[b,k,j]=a_c[k]·r_c[j]; rda0[b,t,j]=r_c[j]·a0[t]; ra0c[b,t,k]=r0[t]·a_c[k];
// rda0self[b,t]=r0[t]·a0[t]; kes0[b,t]; kesc[b,k]
__global__ __launch_bounds__(256) void k_pre(
    const float* __restrict__ alpha, const float* __restrict__ rho,
    const float* __restrict__ lam,   const float* __restrict__ beta,
    const float* __restrict__ theta, const float* __restrict__ gamma_,
    const float* __restrict__ prices,const float* __restrict__ price_table,
    const int* __restrict__ item_ids,const int* __restrict__ itemset,
    const int* __restrict__ userid,
    float* __restrict__ A, float* __restrict__ rda0, float* __restrict__ ra0c,
    float* __restrict__ kesc, float* __restrict__ kes0, float* __restrict__ rda0self)
{
    __shared__ float ac[Kk * 101], rc[Kk * 101];    // stride 101 -> 2-way (free) on LDS
    __shared__ float a0s[Tt * 101], r0s[Tt * 101];
    __shared__ float th[Ee], ga[Ee];

    const int b = blockIdx.x;
    const int uid = userid[b];
    for (int i = threadIdx.x; i < Ee; i += 256) {
        th[i] = theta[(long)uid * Ee + i];
        ga[i] = gamma_[(long)uid * Ee + i];
    }
    for (int i = threadIdx.x; i < Kk * Ee; i += 256) {
        int k = i / Ee, e = i - k * Ee;
        long idx = itemset[b * Kk + k];
        ac[k * 101 + e] = alpha[idx * Ee + e];
        rc[k * 101 + e] = rho[idx * Ee + e];
    }
    for (int i = threadIdx.x; i < Tt * Ee; i += 256) {
        int t = i / Ee, e = i - t * Ee;
        long idx = item_ids[b * Tt + t];
        a0s[t * 101 + e] = alpha[idx * Ee + e];
        r0s[t * 101 + e] = rho[idx * Ee + e];
    }
    __syncthreads();

    for (int p = threadIdx.x; p < Kk * Kk; p += 256) {
        int k = p / Kk, j = p - k * Kk;
        float s = 0.f;
        #pragma unroll 4
        for (int e = 0; e < Ee; ++e) s = fmaf(ac[k * 101 + e], rc[j * 101 + e], s);
        A[((long)b * Kk + k) * Kk + j] = s;
    }
    for (int p = threadIdx.x; p < Tt * Kk; p += 256) {
        int t = p / Kk, j = p - t * Kk;
        float s1 = 0.f, s2 = 0.f;
        #pragma unroll 4
        for (int e = 0; e < Ee; ++e) {
            s1 = fmaf(rc[j * 101 + e], a0s[t * 101 + e], s1);
            s2 = fmaf(r0s[t * 101 + e], ac[j * 101 + e], s2);
        }
        rda0[((long)b * Tt + t) * Kk + j] = s1;
        ra0c[((long)b * Tt + t) * Kk + j] = s2;
    }
    for (int t = threadIdx.x; t < Tt; t += 256) {
        long idx = item_ids[b * Tt + t];
        float s = 0.f, ml = 0.f, mtha = 0.f, mgb = 0.f;
        for (int e = 0; e < Ee; ++e) {
            s    = fmaf(r0s[t * 101 + e], a0s[t * 101 + e], s);
            ml  += lam[idx * Ee + e];
            mtha = fmaf(th[e], a0s[t * 101 + e], mtha);
            mgb  = fmaf(ga[e], beta[idx * Ee + e], mgb);
        }
        rda0self[b * Tt + t] = s;
        kes0[b * Tt + t] = ml * 0.01f + mtha * 0.01f - mgb * 0.01f * logf(prices[b * Tt + t]);
    }
    for (int k = threadIdx.x; k < Kk; k += 256) {
        long idx = itemset[b * Kk + k];
        float ml = 0.f, mtha = 0.f, mgb = 0.f;
        for (int e = 0; e < Ee; ++e) {
            ml  += lam[idx * Ee + e];
            mtha = fmaf(th[e], ac[k * 101 + e], mtha);
            mgb  = fmaf(ga[e], beta[idx * Ee + e], mgb);
        }
        kesc[b * Kk + k] = ml * 0.01f + mtha * 0.01f - mgb * 0.01f * logf(price_table[idx]);
    }
}

// ---------- kernel 3: k-scan + lookahead max + basket ----------
// one wave per (b,t); lane j holds per-j state; scan k sequentially
__global__ __launch_bounds__(256) void k_main(
    const float* __restrict__ A, const float* __restrict__ rda0,
    const float* __restrict__ ra0c, const float* __restrict__ kesc,
    const float* __restrict__ kes0, const float* __restrict__ rda0self,
    const int* __restrict__ item_ids, const int* __restrict__ itemset,
    float* __restrict__ partial)
{
    __shared__ float Als[Kk * Kk];   // A[b] tile, 10 KB
    __shared__ float red[4];
    const int b = blockIdx.x / 5;
    const int tbase = (blockIdx.x % 5) * 4;
    for (int i = threadIdx.x; i < Kk * Kk; i += 256)
        Als[i] = A[(long)b * Kk * Kk + i];
    __syncthreads();

    const int wid = threadIdx.x >> 6, lane = threadIdx.x & 63;
    const int t = tbase + wid;
    const bool valid = lane < Kk;

    const int myitem = item_ids[b * Tt + t];
    const int cj  = valid ? itemset[b * Kk + lane] : -1;
    const float mj  = (valid && cj != myitem) ? 1.f : 0.f;
    const float rj  = valid ? rda0[((long)b * Tt + t) * Kk + lane] : 0.f;
    const float kj  = valid ? kesc[b * Kk + lane] : 0.f;
    const float raj = valid ? ra0c[((long)b * Tt + t) * Kk + lane] : 0.f;
    const float k0      = kes0[b * Tt + t];
    const float r0self  = rda0self[b * Tt + t];

    float cum = 0.f, len = 1.f, cumra = 0.f, basket = 0.f;
    for (int k = 0; k < Kk; ++k) {
        const float mfk = __shfl(mj, k, 64);
        const float akj = valid ? Als[k * Kk + lane] : 0.f;
        cum   = fmaf(mfk, akj, cum);          // inclusive prefix
        len  += mfk;
        cumra = fmaf(mfk, __shfl(raj, k, 64), cumra);

        const float denom   = (len + 1.f) * (float)Ee;
        const float inv_len = 1.f / ((float)Ee * len);
        const float interact0 = (r0self + cumra) * inv_len;
        const float interactc = (__shfl(rj, k, 64) + __shfl(cum, k, 64)) * inv_len;

        const bool elig = valid && (lane > k) && (mj != 0.f);
        const float base = (rj + cum) / denom + kj;
        const float v0 = elig ? base : -1e30f;
        const float vc = elig ? base + akj / denom : -1e30f;
        const float l0v = fmaxf(0.f, wave_max(v0));
        const float lcv = fmaxf(0.f, wave_max(vc));

        const float Kes0 = k0 + interact0 + l0v;
        const float KesC = __shfl(kj, k, 64) + interactc + lcv;
        if (mfk != 0.f) {
            const float x = Kes0 - KesC;
            basket += (x >= 0.f) ? -log1pf(expf(-x)) : x - log1pf(expf(x));
        }
    }
    if (lane == 0) red[wid] = basket;
    __syncthreads();
    if (threadIdx.x == 0) partial[blockIdx.x] = red[0] + red[1] + red[2] + red[3];
}

// ---------- kernel 4: deterministic final reduce ----------
__global__ __launch_bounds__(256) void k_final(
    const float* __restrict__ p1, int n1,
    const float* __restrict__ p3, int n3,
    float* __restrict__ out)
{
    __shared__ double sh[256];
    double s = 0.0;
    for (int i = threadIdx.x; i < n1; i += 256) s += (double)p1[i];
    for (int i = threadIdx.x; i < n3; i += 256) s += (double)p3[i];
    sh[threadIdx.x] = s;
    __syncthreads();
    for (int m = 128; m >= 1; m >>= 1) {
        if (threadIdx.x < m) sh[threadIdx.x] += sh[threadIdx.x + m];
        __syncthreads();
    }
    if (threadIdx.x == 0) out[0] = (float)sh[0];
}

// ---------- launch ----------
extern "C" void kernel_launch(void* const* d_in, const int* in_sizes, int n_in,
                              void* d_out, int out_size, void* d_ws, size_t ws_size,
                              hipStream_t stream) {
    const float* alpha      = (const float*)d_in[0];
    const float* rho        = (const float*)d_in[1];
    const float* lam        = (const float*)d_in[2];
    const float* beta       = (const float*)d_in[3];
    const float* mu_tab     = (const float*)d_in[4];
    const float* theta      = (const float*)d_in[5];
    const float* gamma_     = (const float*)d_in[6];
    const float* w1         = (const float*)d_in[7];
    const float* b1         = (const float*)d_in[8];
    const float* w2         = (const float*)d_in[9];
    const float* b2         = (const float*)d_in[10];
    const float* sigma_list = (const float*)d_in[11];
    // d_in[12] = mu_list (all zeros; folded out)
    const float* prices      = (const float*)d_in[13];
    const float* price_table = (const float*)d_in[14];
    const int*   item_ids    = (const int*)d_in[15];
    const int*   itemset     = (const int*)d_in[16];
    const int*   userid      = (const int*)d_in[17];

    float* ws = (float*)d_ws;
    const size_t offA    = 0;                         // B*K*K
    const size_t offRDA  = offA   + (size_t)Bb*Kk*Kk; // B*T*K
    const size_t offRA0C = offRDA + (size_t)Bb*Tt*Kk; // B*T*K
    const size_t offKESC = offRA0C+ (size_t)Bb*Tt*Kk; // B*K
    const size_t offKES0 = offKESC+ (size_t)Bb*Kk;    // B*T
    const size_t offSELF = offKES0+ (size_t)Bb*Tt;    // B*T
    const size_t offP1   = offSELF+ (size_t)Bb*Tt;    // 256
    const size_t offP3   = offP1  + 256;              // 320

    const int NB1 = 256, NB3 = Bb * 5;

    k_qprior<<<NB1, 256, 0, stream>>>(alpha, rho, lam, beta, mu_tab, theta, gamma_,
                                      w1, b1, w2, b2, sigma_list, itemset, userid,
                                      ws + offP1);
    k_pre<<<Bb, 256, 0, stream>>>(alpha, rho, lam, beta, theta, gamma_,
                                  prices, price_table, item_ids, itemset, userid,
                                  ws + offA, ws + offRDA, ws + offRA0C,
                                  ws + offKESC, ws + offKES0, ws + offSELF);
    k_main<<<NB3, 256, 0, stream>>>(ws + offA, ws + offRDA, ws + offRA0C,
                                    ws + offKESC, ws + offKES0, ws + offSELF,
                                    item_ids, itemset, ws + offP3);
    k_final<<<1, 256, 0, stream>>>(ws + offP1, NB1, ws + offP3, NB3, (float*)d_out);
}

// Round 2
// 99.482 us; speedup vs baseline: 1.4055x; 1.4055x over previous
//
#include <hip/hip_runtime.h>
#include <math.h>

#define Ee 100
#define Hh 64
#define Bb 64
#define Tt 20
#define Kk 50

// ---------- helpers ----------
__device__ __forceinline__ float wave_sum(float v) {
    for (int m = 32; m >= 1; m >>= 1) v += __shfl_xor(v, m, 64);
    return v;
}
__device__ __forceinline__ float wave_max(float v) {
    for (int m = 32; m >= 1; m >>= 1) v = fmaxf(v, __shfl_xor(v, m, 64));
    return v;
}
// uniform-lane broadcast via v_readlane (SALU) instead of ds_bpermute
__device__ __forceinline__ float bcast(float v, int lane) {
    return __uint_as_float(__builtin_amdgcn_readlane(__float_as_uint(v), lane));
}

// ---------- kernel 1: fused Q-network + prior (p_l - q_l) ----------
// rows: 5 segments of B*K (alpha,rho,lam,beta,mu_tab via itemset) + theta,gamma via userid
__global__ __launch_bounds__(256) void k_qprior(
    const float* __restrict__ alpha, const float* __restrict__ rho,
    const float* __restrict__ lam,   const float* __restrict__ beta,
    const float* __restrict__ mu_tab,const float* __restrict__ theta,
    const float* __restrict__ gamma_,const float* __restrict__ w1,
    const float* __restrict__ b1,    const float* __restrict__ w2,
    const float* __restrict__ b2,    const float* __restrict__ sigma_list,
    const int* __restrict__ itemset, const int* __restrict__ userid,
    float* __restrict__ partial)
{
    __shared__ float w1t[Ee * 65];   // [e][j] pad 65: writes consecutive banks, reads 2-way (free)
    __shared__ float xs[4][104];     // per-wave row buffer (float4-aligned rows)
    __shared__ float red[4];
    for (int i = threadIdx.x; i < Hh * Ee; i += 256) {
        int j = i / Ee, e = i - j * Ee;
        w1t[e * 65 + j] = w1[i];     // coalesced read, conflict-free-ish write
    }
    __syncthreads();

    const int lane = threadIdx.x & 63;
    const int wid  = threadIdx.x >> 6;
    const float w2j = w2[lane];
    const float b1j = b1[lane];
    const float b2v = b2[0];

    const int wave   = (blockIdx.x << 2) + wid;
    const int nwaves = gridDim.x << 2;
    const int NROWS  = 5 * Bb * Kk + 2 * Bb;

    float acc = 0.f;
    for (int row = wave; row < NROWS; row += nwaves) {
        const float* tab; int idx; float coef;
        if (row < 5 * Bb * Kk) {
            int seg = row / (Bb * Kk);
            int r   = row - seg * (Bb * Kk);
            idx = itemset[r];
            tab = (seg == 0) ? alpha : (seg == 1) ? rho : (seg == 2) ? lam
                 : (seg == 3) ? beta : mu_tab;
            coef = -0.5f / sigma_list[seg];
        } else {
            int r = row - 5 * Bb * Kk;
            if (r < Bb) { tab = theta;  idx = userid[r];      coef = -0.5f / sigma_list[5]; }
            else        { tab = gamma_; idx = userid[r - Bb]; coef = -0.5f / sigma_list[6]; }
        }
        const float* x = tab + (long)idx * Ee;

        // cooperative vector load of the 100-float row (lanes 0..24)
        float4 xq = make_float4(0.f, 0.f, 0.f, 0.f);
        if (lane < 25) xq = *(const float4*)(x + (lane << 2));
        float ssp = xq.x*xq.x + xq.y*xq.y + xq.z*xq.z + xq.w*xq.w;
        if (lane < 25) *(float4*)(&xs[wid][lane << 2]) = xq;
        asm volatile("s_waitcnt lgkmcnt(0)" ::: "memory");  // wave-internal LDS visibility

        float h = b1j;
        #pragma unroll
        for (int e = 0; e < Ee; ++e)
            h = fmaf(xs[wid][e], w1t[e * 65 + lane], h);    // broadcast + 2-way reads, free

        float ss = wave_sum(ssp);
        float z  = wave_sum(fmaxf(h, 0.f) * w2j) + b2v;
        float q  = 1.f / (1.f + expf(-z));
        acc += coef * ss - q;     // identical on all lanes
    }

    if (lane == 0) red[wid] = acc;
    __syncthreads();
    if (threadIdx.x == 0) partial[blockIdx.x] = red[0] + red[1] + red[2] + red[3];
}

// ---------- kernel 2: per-b precompute (2 blocks per b) ----------
// A[b,k,j]=a_c[k]·r_c[j]; rda0[b,t,j]=r_c[j]·a0[t]; ra0c[b,t,k]=r0[t]·a_c[k];
// rda0self[b,t]=r0[t]·a0[t]; kes0[b,t]; kesc[b,k]
__global__ __launch_bounds__(256) void k_pre(
    const float* __restrict__ alpha, const float* __restrict__ rho,
    const float* __restrict__ lam,   const float* __restrict__ beta,
    const float* __restrict__ theta, const float* __restrict__ gamma_,
    const float* __restrict__ prices,const float* __restrict__ price_table,
    const int* __restrict__ item_ids,const int* __restrict__ itemset,
    const int* __restrict__ userid,
    float* __restrict__ A, float* __restrict__ rda0, float* __restrict__ ra0c,
    float* __restrict__ kesc, float* __restrict__ kes0, float* __restrict__ rda0self)
{
    __shared__ float ac[Kk * 101], rc[Kk * 101];    // stride 101 -> 2-way (free)
    __shared__ float a0s[Tt * 101], r0s[Tt * 101];
    __shared__ float th[Ee], ga[Ee];

    const int b    = blockIdx.x >> 1;
    const int half = blockIdx.x & 1;
    const int uid = userid[b];
    for (int i = threadIdx.x; i < Ee; i += 256) {
        th[i] = theta[(long)uid * Ee + i];
        ga[i] = gamma_[(long)uid * Ee + i];
    }
    for (int i = threadIdx.x; i < Kk * Ee; i += 256) {
        int k = i / Ee, e = i - k * Ee;
        long idx = itemset[b * Kk + k];
        ac[k * 101 + e] = alpha[idx * Ee + e];
        rc[k * 101 + e] = rho[idx * Ee + e];
    }
    for (int i = threadIdx.x; i < Tt * Ee; i += 256) {
        int t = i / Ee, e = i - t * Ee;
        long idx = item_ids[b * Tt + t];
        a0s[t * 101 + e] = alpha[idx * Ee + e];
        r0s[t * 101 + e] = rho[idx * Ee + e];
    }
    __syncthreads();

    // A: this block handles k in [half*25, half*25+25)
    for (int p = threadIdx.x; p < (Kk / 2) * Kk; p += 256) {
        int k = p / Kk + half * (Kk / 2), j = p % Kk;
        float s = 0.f;
        #pragma unroll 4
        for (int e = 0; e < Ee; ++e) s = fmaf(ac[k * 101 + e], rc[j * 101 + e], s);
        A[((long)b * Kk + k) * Kk + j] = s;
    }
    // rda0/ra0c: t in [half*10, half*10+10)
    for (int p = threadIdx.x; p < (Tt / 2) * Kk; p += 256) {
        int t = p / Kk + half * (Tt / 2), j = p % Kk;
        float s1 = 0.f, s2 = 0.f;
        #pragma unroll 4
        for (int e = 0; e < Ee; ++e) {
            s1 = fmaf(rc[j * 101 + e], a0s[t * 101 + e], s1);
            s2 = fmaf(r0s[t * 101 + e], ac[j * 101 + e], s2);
        }
        rda0[((long)b * Tt + t) * Kk + j] = s1;
        ra0c[((long)b * Tt + t) * Kk + j] = s2;
    }
    for (int t = threadIdx.x + half * (Tt / 2); t < (half + 1) * (Tt / 2); t += 256) {
        long idx = item_ids[b * Tt + t];
        float s = 0.f, ml = 0.f, mtha = 0.f, mgb = 0.f;
        for (int e = 0; e < Ee; ++e) {
            s    = fmaf(r0s[t * 101 + e], a0s[t * 101 + e], s);
            ml  += lam[idx * Ee + e];
            mtha = fmaf(th[e], a0s[t * 101 + e], mtha);
            mgb  = fmaf(ga[e], beta[idx * Ee + e], mgb);
        }
        rda0self[b * Tt + t] = s;
        kes0[b * Tt + t] = ml * 0.01f + mtha * 0.01f - mgb * 0.01f * logf(prices[b * Tt + t]);
    }
    for (int k = threadIdx.x + half * (Kk / 2); k < (half + 1) * (Kk / 2); k += 256) {
        long idx = itemset[b * Kk + k];
        float ml = 0.f, mtha = 0.f, mgb = 0.f;
        for (int e = 0; e < Ee; ++e) {
            ml  += lam[idx * Ee + e];
            mtha = fmaf(th[e], ac[k * 101 + e], mtha);
            mgb  = fmaf(ga[e], beta[idx * Ee + e], mgb);
        }
        kesc[b * Kk + k] = ml * 0.01f + mtha * 0.01f - mgb * 0.01f * logf(price_table[idx]);
    }
}

// ---------- kernel 3: k-scan + lookahead max + basket ----------
// one wave per (b,t); lane j holds per-j state; scan k sequentially
__global__ __launch_bounds__(256) void k_main(
    const float* __restrict__ A, const float* __restrict__ rda0,
    const float* __restrict__ ra0c, const float* __restrict__ kesc,
    const float* __restrict__ kes0, const float* __restrict__ rda0self,
    const int* __restrict__ item_ids, const int* __restrict__ itemset,
    float* __restrict__ partial)
{
    __shared__ float Als[Kk * Kk];   // A[b] tile, 10 KB
    __shared__ float red[4];
    const int b = blockIdx.x / 5;
    const int tbase = (blockIdx.x % 5) * 4;
    for (int i = threadIdx.x; i < Kk * Kk; i += 256)
        Als[i] = A[(long)b * Kk * Kk + i];
    __syncthreads();

    const int wid = threadIdx.x >> 6, lane = threadIdx.x & 63;
    const int t = tbase + wid;
    const bool valid = lane < Kk;

    const int myitem = item_ids[b * Tt + t];
    const int cj  = valid ? itemset[b * Kk + lane] : -1;
    const float mj  = (valid && cj != myitem) ? 1.f : 0.f;
    const float rj  = valid ? rda0[((long)b * Tt + t) * Kk + lane] : 0.f;
    const float kj  = valid ? kesc[b * Kk + lane] : 0.f;
    const float raj = valid ? ra0c[((long)b * Tt + t) * Kk + lane] : 0.f;
    const float k0      = kes0[b * Tt + t];
    const float r0self  = rda0self[b * Tt + t];

    float cum = 0.f, len = 1.f, cumra = 0.f, basket = 0.f;
    #pragma unroll 2
    for (int k = 0; k < Kk; ++k) {
        const float mfk = bcast(mj, k);
        const float akj = valid ? Als[k * Kk + lane] : 0.f;
        cum   = fmaf(mfk, akj, cum);          // inclusive prefix
        len  += mfk;
        cumra = fmaf(mfk, bcast(raj, k), cumra);

        const float denom   = (len + 1.f) * (float)Ee;
        const float inv_len = 1.f / ((float)Ee * len);
        const float interact0 = (r0self + cumra) * inv_len;
        const float interactc = (bcast(rj, k) + bcast(cum, k)) * inv_len;

        const bool elig = valid && (lane > k) && (mj != 0.f);
        const float base = (rj + cum) / denom + kj;
        const float v0 = elig ? base : -1e30f;
        const float vc = elig ? base + akj / denom : -1e30f;
        const float l0v = fmaxf(0.f, wave_max(v0));
        const float lcv = fmaxf(0.f, wave_max(vc));

        const float Kes0 = k0 + interact0 + l0v;
        const float KesC = bcast(kj, k) + interactc + lcv;
        if (mfk != 0.f) {
            const float x = Kes0 - KesC;
            basket += (x >= 0.f) ? -log1pf(expf(-x)) : x - log1pf(expf(x));
        }
    }
    if (lane == 0) red[wid] = basket;
    __syncthreads();
    if (threadIdx.x == 0) partial[blockIdx.x] = red[0] + red[1] + red[2] + red[3];
}

// ---------- kernel 4: deterministic final reduce ----------
__global__ __launch_bounds__(256) void k_final(
    const float* __restrict__ p1, int n1,
    const float* __restrict__ p3, int n3,
    float* __restrict__ out)
{
    __shared__ double sh[256];
    double s = 0.0;
    for (int i = threadIdx.x; i < n1; i += 256) s += (double)p1[i];
    for (int i = threadIdx.x; i < n3; i += 256) s += (double)p3[i];
    sh[threadIdx.x] = s;
    __syncthreads();
    for (int m = 128; m >= 1; m >>= 1) {
        if (threadIdx.x < m) sh[threadIdx.x] += sh[threadIdx.x + m];
        __syncthreads();
    }
    if (threadIdx.x == 0) out[0] = (float)sh[0];
}

// ---------- launch ----------
extern "C" void kernel_launch(void* const* d_in, const int* in_sizes, int n_in,
                              void* d_out, int out_size, void* d_ws, size_t ws_size,
                              hipStream_t stream) {
    const float* alpha      = (const float*)d_in[0];
    const float* rho        = (const float*)d_in[1];
    const float* lam        = (const float*)d_in[2];
    const float* beta       = (const float*)d_in[3];
    const float* mu_tab     = (const float*)d_in[4];
    const float* theta      = (const float*)d_in[5];
    const float* gamma_     = (const float*)d_in[6];
    const float* w1         = (const float*)d_in[7];
    const float* b1         = (const float*)d_in[8];
    const float* w2         = (const float*)d_in[9];
    const float* b2         = (const float*)d_in[10];
    const float* sigma_list = (const float*)d_in[11];
    // d_in[12] = mu_list (all zeros; folded out)
    const float* prices      = (const float*)d_in[13];
    const float* price_table = (const float*)d_in[14];
    const int*   item_ids    = (const int*)d_in[15];
    const int*   itemset     = (const int*)d_in[16];
    const int*   userid     = (const int*)d_in[17];

    float* ws = (float*)d_ws;
    const size_t offA    = 0;                         // B*K*K
    const size_t offRDA  = offA   + (size_t)Bb*Kk*Kk; // B*T*K
    const size_t offRA0C = offRDA + (size_t)Bb*Tt*Kk; // B*T*K
    const size_t offKESC = offRA0C+ (size_t)Bb*Tt*Kk; // B*K
    const size_t offKES0 = offKESC+ (size_t)Bb*Kk;    // B*T
    const size_t offSELF = offKES0+ (size_t)Bb*Tt;    // B*T
    const size_t offP1   = offSELF+ (size_t)Bb*Tt;    // NB1
    const size_t offP3   = offP1  + 1024;             // NB3

    const int NB1 = 1024, NB3 = Bb * 5;

    k_qprior<<<NB1, 256, 0, stream>>>(alpha, rho, lam, beta, mu_tab, theta, gamma_,
                                      w1, b1, w2, b2, sigma_list, itemset, userid,
                                      ws + offP1);
    k_pre<<<Bb * 2, 256, 0, stream>>>(alpha, rho, lam, beta, theta, gamma_,
                                      prices, price_table, item_ids, itemset, userid,
                                      ws + offA, ws + offRDA, ws + offRA0C,
                                      ws + offKESC, ws + offKES0, ws + offSELF);
    k_main<<<NB3, 256, 0, stream>>>(ws + offA, ws + offRDA, ws + offRA0C,
                                    ws + offKESC, ws + offKES0, ws + offSELF,
                                    item_ids, itemset, ws + offP3);
    k_final<<<1, 256, 0, stream>>>(ws + offP1, NB1, ws + offP3, NB3, (float*)d_out);
}

// Round 3
// 71.343 us; speedup vs baseline: 1.9599x; 1.3944x over previous
//
#include <hip/hip_runtime.h>
#include <math.h>

#define Ee 100
#define Hh 64
#define Bb 64
#define Tt 20
#define Kk 50
#define NROWS (5*Bb*Kk + 2*Bb)   // 16128

// ---------- helpers ----------
__device__ __forceinline__ float wave_sum(float v) {
    #pragma unroll
    for (int m = 32; m >= 1; m >>= 1) v += __shfl_xor(v, m, 64);
    return v;
}

// ---------- kernel 1: fused Q-network + prior (p_l - q_l) ----------
// w1 lives in registers: lane j holds w1[j][0..99]. x rows broadcast via tiny LDS buffer.
__global__ __launch_bounds__(256) void k_qprior(
    const float* __restrict__ alpha, const float* __restrict__ rho,
    const float* __restrict__ lam,   const float* __restrict__ beta,
    const float* __restrict__ mu_tab,const float* __restrict__ theta,
    const float* __restrict__ gamma_,const float* __restrict__ w1,
    const float* __restrict__ b1,    const float* __restrict__ w2,
    const float* __restrict__ b2,    const float* __restrict__ sigma_list,
    const int* __restrict__ itemset, const int* __restrict__ userid,
    float* __restrict__ partial)
{
    __shared__ float xs[4][104];
    __shared__ float red[4];

    const int lane = threadIdx.x & 63;
    const int wid  = threadIdx.x >> 6;

    float w1r[Ee];
    #pragma unroll
    for (int i = 0; i < Ee/4; ++i) {
        float4 wv = *(const float4*)(w1 + lane*Ee + i*4);
        w1r[i*4+0] = wv.x; w1r[i*4+1] = wv.y; w1r[i*4+2] = wv.z; w1r[i*4+3] = wv.w;
    }
    const float w2j = w2[lane];
    const float b1j = b1[lane];
    const float b2v = b2[0];

    const int wave   = blockIdx.x*4 + wid;
    const int nwaves = gridDim.x*4;

    auto desc = [&](int row, const float*& x, float& coef) {
        if (row < 5*Bb*Kk) {
            int seg = row / (Bb*Kk);
            int r   = row - seg*(Bb*Kk);
            int idx = itemset[r];
            const float* tab = (seg==0)?alpha:(seg==1)?rho:(seg==2)?lam:(seg==3)?beta:mu_tab;
            x = tab + (long)idx*Ee;
            coef = -0.5f / sigma_list[seg];
        } else {
            int r = row - 5*Bb*Kk;
            if (r < Bb) { x = theta  + (long)userid[r]*Ee;    coef = -0.5f/sigma_list[5]; }
            else        { x = gamma_ + (long)userid[r-Bb]*Ee; coef = -0.5f/sigma_list[6]; }
        }
    };

    float acc = 0.f;
    const float* xp = nullptr; float coef = 0.f;
    float4 cur = make_float4(0.f,0.f,0.f,0.f);
    if (wave < NROWS) {
        desc(wave, xp, coef);
        if (lane < 25) cur = *(const float4*)(xp + (lane<<2));
    }
    for (int row = wave; row < NROWS; row += nwaves) {
        if (lane < 25) *(float4*)(&xs[wid][lane<<2]) = cur;
        float ssp = cur.x*cur.x + cur.y*cur.y + cur.z*cur.z + cur.w*cur.w;
        float curcoef = coef;
        float4 nxt = make_float4(0.f,0.f,0.f,0.f);
        int next = row + nwaves;
        if (next < NROWS) {                 // prefetch next row; latency hides under h-loop
            desc(next, xp, coef);
            if (lane < 25) nxt = *(const float4*)(xp + (lane<<2));
        }
        asm volatile("s_waitcnt lgkmcnt(0)" ::: "memory");   // xs visible wave-internally

        float h0 = b1j, h1 = 0.f, h2 = 0.f, h3 = 0.f;
        #pragma unroll
        for (int i = 0; i < Ee/4; ++i) {
            float4 xv = *(const float4*)(&xs[wid][i*4]);     // b128 broadcast read
            h0 = fmaf(xv.x, w1r[i*4+0], h0);
            h1 = fmaf(xv.y, w1r[i*4+1], h1);
            h2 = fmaf(xv.z, w1r[i*4+2], h2);
            h3 = fmaf(xv.w, w1r[i*4+3], h3);
        }
        float h  = (h0 + h1) + (h2 + h3);
        float ss = wave_sum(ssp);
        float z  = wave_sum(fmaxf(h, 0.f) * w2j) + b2v;
        float q  = 1.f / (1.f + expf(-z));
        acc += curcoef*ss - q;               // identical on all lanes
        cur = nxt;
    }
    if (lane == 0) red[wid] = acc;
    __syncthreads();
    if (threadIdx.x == 0) partial[blockIdx.x] = red[0]+red[1]+red[2]+red[3];
}

// ---------- kernel 2: per-b precompute (4 blocks per b) ----------
__global__ __launch_bounds__(256) void k_pre(
    const float* __restrict__ alpha, const float* __restrict__ rho,
    const float* __restrict__ lam,   const float* __restrict__ beta,
    const float* __restrict__ theta, const float* __restrict__ gamma_,
    const float* __restrict__ prices,const float* __restrict__ price_table,
    const int* __restrict__ item_ids,const int* __restrict__ itemset,
    const int* __restrict__ userid,
    float* __restrict__ A, float* __restrict__ rda0, float* __restrict__ ra0c,
    float* __restrict__ kesc, float* __restrict__ kes0, float* __restrict__ rda0self)
{
    __shared__ float ac[Kk*101], rc[Kk*101];   // stride 101 -> conflict-free column access
    __shared__ float a0s[5*101], r0s[5*101];
    __shared__ float th[Ee], ga[Ee];

    const int b = blockIdx.x >> 2, q = blockIdx.x & 3;
    const int kcnt = (q < 2) ? 13 : 12;
    const int kbeg = q*12 + ((q < 2) ? q : 2);
    const int tbeg = q*5;
    const long uid = userid[b];

    for (int i = threadIdx.x; i < Ee; i += 256) {
        th[i] = theta[uid*Ee+i];
        ga[i] = gamma_[uid*Ee+i];
    }
    for (int i = threadIdx.x; i < Kk*Ee; i += 256) {
        int k = i/Ee, e = i - k*Ee;
        long idx = itemset[b*Kk+k];
        ac[k*101+e] = alpha[idx*Ee+e];
        rc[k*101+e] = rho[idx*Ee+e];
    }
    for (int i = threadIdx.x; i < 5*Ee; i += 256) {
        int tl = i/Ee, e = i - tl*Ee;
        long idx = item_ids[b*Tt + tbeg + tl];
        a0s[tl*101+e] = alpha[idx*Ee+e];
        r0s[tl*101+e] = rho[idx*Ee+e];
    }
    __syncthreads();

    for (int p = threadIdx.x; p < kcnt*Kk; p += 256) {
        int k = kbeg + p/Kk, j = p - (p/Kk)*Kk;
        float s = 0.f;
        #pragma unroll 4
        for (int e = 0; e < Ee; ++e) s = fmaf(ac[k*101+e], rc[j*101+e], s);
        A[((long)b*Kk+k)*Kk+j] = s;
    }
    for (int p = threadIdx.x; p < 5*Kk; p += 256) {
        int tl = p/Kk, j = p - tl*Kk;
        float s1 = 0.f, s2 = 0.f;
        #pragma unroll 4
        for (int e = 0; e < Ee; ++e) {
            s1 = fmaf(rc[j*101+e], a0s[tl*101+e], s1);
            s2 = fmaf(r0s[tl*101+e], ac[j*101+e], s2);
        }
        int t = tbeg + tl;
        rda0[((long)b*Tt+t)*Kk+j] = s1;
        ra0c[((long)b*Tt+t)*Kk+j] = s2;
    }
    // wave-parallel tail tasks: 5 t-tasks + kcnt k-tasks
    const int wid = threadIdx.x >> 6, lane = threadIdx.x & 63;
    for (int task = wid; task < 5 + kcnt; task += 4) {
        if (task < 5) {
            int tl = task, t = tbeg + tl;
            long idx = item_ids[b*Tt+t];
            float s=0.f, ml=0.f, mtha=0.f, mgb=0.f;
            if (lane < Kk) {
                #pragma unroll
                for (int u = 0; u < 2; ++u) {
                    int e = lane + u*Kk;
                    float a0v = a0s[tl*101+e], r0v = r0s[tl*101+e];
                    s    = fmaf(r0v, a0v, s);
                    ml  += lam[idx*Ee+e];
                    mtha = fmaf(th[e], a0v, mtha);
                    mgb  = fmaf(ga[e], beta[idx*Ee+e], mgb);
                }
            }
            s = wave_sum(s); ml = wave_sum(ml); mtha = wave_sum(mtha); mgb = wave_sum(mgb);
            if (lane == 0) {
                rda0self[b*Tt+t] = s;
                kes0[b*Tt+t] = 0.01f*ml + 0.01f*mtha - 0.01f*mgb*logf(prices[b*Tt+t]);
            }
        } else {
            int k = kbeg + (task - 5);
            long idx = itemset[b*Kk+k];
            float ml=0.f, mtha=0.f, mgb=0.f;
            if (lane < Kk) {
                #pragma unroll
                for (int u = 0; u < 2; ++u) {
                    int e = lane + u*Kk;
                    ml  += lam[idx*Ee+e];
                    mtha = fmaf(th[e], ac[k*101+e], mtha);
                    mgb  = fmaf(ga[e], beta[idx*Ee+e], mgb);
                }
            }
            ml = wave_sum(ml); mtha = wave_sum(mtha); mgb = wave_sum(mgb);
            if (lane == 0)
                kesc[b*Kk+k] = 0.01f*ml + 0.01f*mtha - 0.01f*mgb*logf(price_table[idx]);
        }
    }
}

// ---------- kernel 3: one wave per (b,t); two-phase scan, no per-step cross-lane ops ----------
__global__ __launch_bounds__(64) void k_main(
    const float* __restrict__ A, const float* __restrict__ rda0,
    const float* __restrict__ ra0c, const float* __restrict__ kesc,
    const float* __restrict__ kes0, const float* __restrict__ rda0self,
    const int* __restrict__ item_ids, const int* __restrict__ itemset,
    float* __restrict__ partial)
{
    __shared__ float Als[Kk*51];     // A[b], padded 51 (odd stride -> conflict-free columns)
    __shared__ float Cum[Kk*51];     // prefix sums, same layout
    __shared__ float2 js[Kk];        // per-j scalars {rda0_j, kesc_j}

    const int bt = blockIdx.x;
    const int b  = bt / Tt;
    const int lane = threadIdx.x;

    for (int i = lane; i < Kk*Kk; i += 64) {
        int k = i / Kk;
        Als[k*51 + (i - k*Kk)] = A[(long)b*Kk*Kk + i];
    }

    const int  myitem = item_ids[bt];
    const bool valid  = lane < Kk;
    const int  cj     = valid ? itemset[b*Kk+lane] : -1;
    const bool mj     = valid && (cj != myitem);
    const unsigned long long mask = __ballot(mj);

    const float rj_own = valid ? rda0[(long)bt*Kk+lane] : 0.f;
    const float kc_own = valid ? kesc[b*Kk+lane] : 0.f;
    const float raj    = valid ? ra0c[(long)bt*Kk+lane] : 0.f;
    if (valid) js[lane] = make_float2(rj_own, kc_own);

    // len via mbcnt (no scan): 1 + #set bits at or below own lane
    const unsigned mlo = (unsigned)mask, mhi = (unsigned)(mask >> 32);
    const int below = __builtin_amdgcn_mbcnt_hi(mhi, __builtin_amdgcn_mbcnt_lo(mlo, 0));
    const float len    = 1.f + (float)below + (mj ? 1.f : 0.f);
    const float invden = 1.f / ((len + 1.f) * (float)Ee);
    const float invlen = 1.f / ((float)Ee * len);

    // cumra: inclusive prefix of mf*raj (once)
    float pv = mj ? raj : 0.f;
    #pragma unroll
    for (int off = 1; off <= 32; off <<= 1) {
        float u = __shfl_up(pv, off, 64);
        if (lane >= off) pv += u;
    }
    const float cumra  = pv;
    const float r0self = rda0self[bt];
    const float k0     = kes0[bt];

    asm volatile("s_waitcnt lgkmcnt(0)" ::: "memory");   // Als/js ready (single wave, no barrier)

    // phase 1: lane = j, serial k, cum prefix -> Cum[k][j]
    if (valid) {
        float cum = 0.f;
        #pragma unroll 5
        for (int k = 0; k < Kk; ++k) {
            float mfk = ((mask >> k) & 1ull) ? 1.0f : 0.0f;
            cum = fmaf(mfk, Als[k*51 + lane], cum);
            Cum[k*51 + lane] = cum;
        }
    }
    asm volatile("s_waitcnt lgkmcnt(0)" ::: "memory");

    // phase 2: lane = k, serial j, running per-lane maxes (zero cross-lane ops)
    const int lc = valid ? lane : (Kk-1);
    float max0 = -3e38f, maxc = -3e38f, diag = 0.f;
    #pragma unroll 2
    for (int j = 0; j < Kk; ++j) {
        float c = Cum[lc*51 + j];                 // column read, conflict-free
        if (j == lane) diag = c;                  // Cum[k][k]
        if ((mask >> j) & 1ull) {                 // uniform branch: m[j]
            float  a  = Als[lc*51 + j];
            float2 sj = js[j];                    // broadcast
            float v0 = fmaf(c + 2.f*sj.x, invden, sj.y);      // (D+rda0)/denom + kesc
            float vc = fmaf(a - sj.x,    invden, v0);         // (D+A_kj)/denom + kesc
            if (lane < j) { max0 = fmaxf(max0, v0); maxc = fmaxf(maxc, vc); }
        }
    }

    // epilogue: all 50 log-sigmoids in parallel
    float look0 = fmaxf(0.f, max0);
    float lookc = fmaxf(0.f, maxc);
    float Kes0 = k0     + fmaf(r0self + cumra, invlen, look0);
    float KesC = kc_own + fmaf(rj_own + diag,  invlen, lookc);
    float x = Kes0 - KesC;
    float term = (x >= 0.f) ? -log1pf(expf(-x)) : (x - log1pf(expf(x)));
    float contrib = mj ? term : 0.f;
    float s = wave_sum(contrib);
    if (lane == 0) partial[bt] = s;
}

// ---------- kernel 4: deterministic final reduce ----------
__global__ __launch_bounds__(256) void k_final(
    const float* __restrict__ p1, int n1,
    const float* __restrict__ p3, int n3,
    float* __restrict__ out)
{
    __shared__ double sh[256];
    double s = 0.0;
    for (int i = threadIdx.x; i < n1; i += 256) s += (double)p1[i];
    for (int i = threadIdx.x; i < n3; i += 256) s += (double)p3[i];
    sh[threadIdx.x] = s;
    __syncthreads();
    for (int m = 128; m >= 1; m >>= 1) {
        if (threadIdx.x < m) sh[threadIdx.x] += sh[threadIdx.x + m];
        __syncthreads();
    }
    if (threadIdx.x == 0) out[0] = (float)sh[0];
}

// ---------- launch ----------
extern "C" void kernel_launch(void* const* d_in, const int* in_sizes, int n_in,
                              void* d_out, int out_size, void* d_ws, size_t ws_size,
                              hipStream_t stream) {
    const float* alpha      = (const float*)d_in[0];
    const float* rho        = (const float*)d_in[1];
    const float* lam        = (const float*)d_in[2];
    const float* beta       = (const float*)d_in[3];
    const float* mu_tab     = (const float*)d_in[4];
    const float* theta      = (const float*)d_in[5];
    const float* gamma_     = (const float*)d_in[6];
    const float* w1         = (const float*)d_in[7];
    const float* b1         = (const float*)d_in[8];
    const float* w2         = (const float*)d_in[9];
    const float* b2         = (const float*)d_in[10];
    const float* sigma_list = (const float*)d_in[11];
    // d_in[12] = mu_list (all zeros; folded out)
    const float* prices      = (const float*)d_in[13];
    const float* price_table = (const float*)d_in[14];
    const int*   item_ids    = (const int*)d_in[15];
    const int*   itemset     = (const int*)d_in[16];
    const int*   userid      = (const int*)d_in[17];

    float* ws = (float*)d_ws;
    const size_t offA    = 0;                         // B*K*K
    const size_t offRDA  = offA   + (size_t)Bb*Kk*Kk; // B*T*K
    const size_t offRA0C = offRDA + (size_t)Bb*Tt*Kk; // B*T*K
    const size_t offKESC = offRA0C+ (size_t)Bb*Tt*Kk; // B*K
    const size_t offKES0 = offKESC+ (size_t)Bb*Kk;    // B*T
    const size_t offSELF = offKES0+ (size_t)Bb*Tt;    // B*T
    const size_t offP1   = offSELF+ (size_t)Bb*Tt;    // NB1
    const size_t offP3   = offP1  + 1024;             // NB3

    const int NB1 = 1024, NB3 = Bb * Tt;   // 1280

    k_qprior<<<NB1, 256, 0, stream>>>(alpha, rho, lam, beta, mu_tab, theta, gamma_,
                                      w1, b1, w2, b2, sigma_list, itemset, userid,
                                      ws + offP1);
    k_pre<<<Bb * 4, 256, 0, stream>>>(alpha, rho, lam, beta, theta, gamma_,
                                      prices, price_table, item_ids, itemset, userid,
                                      ws + offA, ws + offRDA, ws + offRA0C,
                                      ws + offKESC, ws + offKES0, ws + offSELF);
    k_main<<<NB3, 64, 0, stream>>>(ws + offA, ws + offRDA, ws + offRA0C,
                                   ws + offKESC, ws + offKES0, ws + offSELF,
                                   item_ids, itemset, ws + offP3);
    k_final<<<1, 256, 0, stream>>>(ws + offP1, NB1, ws + offP3, NB3, (float*)d_out);
}

// Round 4
// 52.618 us; speedup vs baseline: 2.6573x; 1.3559x over previous
//
#include <hip/hip_runtime.h>
#include <math.h>

#define Ee 100
#define Hh 64
#define Bb 64
#define Tt 20
#define Kk 50
#define NROWS (5*Bb*Kk + 2*Bb)   // 16128
#define NPAIRS (NROWS/2)         // 8064
#define PREBLKS 256
#define QBLKS   1024

// ---------- helpers ----------
__device__ __forceinline__ float wave_sum(float v) {
    #pragma unroll
    for (int m = 32; m >= 1; m >>= 1) v += __shfl_xor(v, m, 64);
    return v;
}

// ---------- kernel A: fused {Q-network+prior} and {per-b precompute} ----------
// blocks [0,256): pre role (4 blocks per b). blocks [256,1280): qprior role.
// LDS aliased: pre needs 11310 floats, qprior needs 7236.
__global__ __launch_bounds__(256) void k_fused1(
    const float* __restrict__ alpha, const float* __restrict__ rho,
    const float* __restrict__ lam,   const float* __restrict__ beta,
    const float* __restrict__ mu_tab,const float* __restrict__ theta,
    const float* __restrict__ gamma_,const float* __restrict__ w1,
    const float* __restrict__ b1,    const float* __restrict__ w2,
    const float* __restrict__ b2,    const float* __restrict__ sigma_list,
    const float* __restrict__ prices,const float* __restrict__ price_table,
    const int* __restrict__ item_ids,const int* __restrict__ itemset,
    const int* __restrict__ userid,
    float* __restrict__ A, float* __restrict__ rda0, float* __restrict__ ra0c,
    float* __restrict__ kesc, float* __restrict__ kes0, float* __restrict__ rda0self,
    float* __restrict__ partialQ)
{
    __shared__ float buf[11312];
    const int lane = threadIdx.x & 63;
    const int wid  = threadIdx.x >> 6;

    if (blockIdx.x < PREBLKS) {
        // ================= pre role =================
        float* ac  = buf;            // Kk*101
        float* rc  = buf + 5050;     // Kk*101
        float* a0s = buf + 10100;    // 5*101
        float* r0s = buf + 10605;    // 5*101
        float* th  = buf + 11110;    // Ee
        float* ga  = buf + 11210;    // Ee

        const int b = blockIdx.x >> 2, q = blockIdx.x & 3;
        const int kcnt = (q < 2) ? 13 : 12;
        const int kbeg = q*12 + ((q < 2) ? q : 2);
        const int tbeg = q*5;
        const long uid = userid[b];

        for (int i = threadIdx.x; i < Ee; i += 256) {
            th[i] = theta[uid*Ee+i];
            ga[i] = gamma_[uid*Ee+i];
        }
        for (int i = threadIdx.x; i < Kk*Ee; i += 256) {
            int k = i/Ee, e = i - k*Ee;
            long idx = itemset[b*Kk+k];
            ac[k*101+e] = alpha[idx*Ee+e];
            rc[k*101+e] = rho[idx*Ee+e];
        }
        for (int i = threadIdx.x; i < 5*Ee; i += 256) {
            int tl = i/Ee, e = i - tl*Ee;
            long idx = item_ids[b*Tt + tbeg + tl];
            a0s[tl*101+e] = alpha[idx*Ee+e];
            r0s[tl*101+e] = rho[idx*Ee+e];
        }
        __syncthreads();

        for (int p = threadIdx.x; p < kcnt*Kk; p += 256) {
            int k = kbeg + p/Kk, j = p - (p/Kk)*Kk;
            float s = 0.f;
            #pragma unroll 4
            for (int e = 0; e < Ee; ++e) s = fmaf(ac[k*101+e], rc[j*101+e], s);
            A[((long)b*Kk+k)*Kk+j] = s;
        }
        for (int p = threadIdx.x; p < 5*Kk; p += 256) {
            int tl = p/Kk, j = p - tl*Kk;
            float s1 = 0.f, s2 = 0.f;
            #pragma unroll 4
            for (int e = 0; e < Ee; ++e) {
                s1 = fmaf(rc[j*101+e], a0s[tl*101+e], s1);
                s2 = fmaf(r0s[tl*101+e], ac[j*101+e], s2);
            }
            int t = tbeg + tl;
            rda0[((long)b*Tt+t)*Kk+j] = s1;
            ra0c[((long)b*Tt+t)*Kk+j] = s2;
        }
        for (int task = wid; task < 5 + kcnt; task += 4) {
            if (task < 5) {
                int tl = task, t = tbeg + tl;
                long idx = item_ids[b*Tt+t];
                float s=0.f, ml=0.f, mtha=0.f, mgb=0.f;
                if (lane < Kk) {
                    #pragma unroll
                    for (int u = 0; u < 2; ++u) {
                        int e = lane + u*Kk;
                        float a0v = a0s[tl*101+e], r0v = r0s[tl*101+e];
                        s    = fmaf(r0v, a0v, s);
                        ml  += lam[idx*Ee+e];
                        mtha = fmaf(th[e], a0v, mtha);
                        mgb  = fmaf(ga[e], beta[idx*Ee+e], mgb);
                    }
                }
                s = wave_sum(s); ml = wave_sum(ml); mtha = wave_sum(mtha); mgb = wave_sum(mgb);
                if (lane == 0) {
                    rda0self[b*Tt+t] = s;
                    kes0[b*Tt+t] = 0.01f*ml + 0.01f*mtha - 0.01f*mgb*logf(prices[b*Tt+t]);
                }
            } else {
                int k = kbeg + (task - 5);
                long idx = itemset[b*Kk+k];
                float ml=0.f, mtha=0.f, mgb=0.f;
                if (lane < Kk) {
                    #pragma unroll
                    for (int u = 0; u < 2; ++u) {
                        int e = lane + u*Kk;
                        ml  += lam[idx*Ee+e];
                        mtha = fmaf(th[e], ac[k*101+e], mtha);
                        mgb  = fmaf(ga[e], beta[idx*Ee+e], mgb);
                    }
                }
                ml = wave_sum(ml); mtha = wave_sum(mtha); mgb = wave_sum(mgb);
                if (lane == 0)
                    kesc[b*Kk+k] = 0.01f*ml + 0.01f*mtha - 0.01f*mgb*logf(price_table[idx]);
            }
        }
    } else {
        // ================= qprior role =================
        // w1s: natural row-major [64][100]. Row stride 400B (16B aligned);
        // 100 mod 32 = 4 -> per-wave ds_read_b128 of own row hits the 8-cycle
        // minimum (8 lanes per 4-bank window, 8 windows), zero conflict overhead.
        float* w1s = buf;                  // 6400
        float* xsA = buf + 6400 + wid*208; // 104 per row, 2 rows per wave
        float* xsB = xsA + 104;
        float* red = buf + 7232;           // 4

        for (int i = threadIdx.x; i < Hh*Ee; i += 256) w1s[i] = w1[i];
        __syncthreads();

        const float w2j = w2[lane];
        const float b1j = b1[lane];
        const float b2v = b2[0];

        auto desc = [&](int row, const float*& x, float& coef) {
            if (row < 5*Bb*Kk) {
                int seg = row / (Bb*Kk);
                int r   = row - seg*(Bb*Kk);
                int idx = itemset[r];
                const float* tab = (seg==0)?alpha:(seg==1)?rho:(seg==2)?lam:(seg==3)?beta:mu_tab;
                x = tab + (long)idx*Ee;
                coef = -0.5f / sigma_list[seg];
            } else {
                int r = row - 5*Bb*Kk;
                if (r < Bb) { x = theta  + (long)userid[r]*Ee;    coef = -0.5f/sigma_list[5]; }
                else        { x = gamma_ + (long)userid[r-Bb]*Ee; coef = -0.5f/sigma_list[6]; }
            }
        };

        const int wave = (blockIdx.x - PREBLKS)*4 + wid;
        const bool ldA = (lane < 25);
        const bool ldB = (lane >= 32) && (lane < 57);

        float acc = 0.f;
        for (int p = wave; p < NPAIRS; p += QBLKS*4) {
            const float *xpA, *xpB; float coefA, coefB;
            desc(2*p,   xpA, coefA);
            desc(2*p+1, xpB, coefB);

            float4 xq = make_float4(0.f,0.f,0.f,0.f);
            if (ldA)      xq = *(const float4*)(xpA + (lane<<2));
            else if (ldB) xq = *(const float4*)(xpB + ((lane-32)<<2));
            float ssp = xq.x*xq.x + xq.y*xq.y + xq.z*xq.z + xq.w*xq.w;
            if (ldA)      *(float4*)(&xsA[lane<<2])      = xq;
            else if (ldB) *(float4*)(&xsB[(lane-32)<<2]) = xq;
            asm volatile("s_waitcnt lgkmcnt(0)" ::: "memory");   // wave-internal LDS visibility

            float hA0 = b1j, hA1 = 0.f, hB0 = b1j, hB1 = 0.f;
            #pragma unroll
            for (int i = 0; i < Ee/4; ++i) {
                float4 wv = *(const float4*)(&w1s[lane*Ee + i*4]);  // own row, b128
                float4 xa = *(const float4*)(&xsA[i*4]);            // broadcast
                float4 xb = *(const float4*)(&xsB[i*4]);            // broadcast
                hA0 = fmaf(wv.x, xa.x, hA0); hA1 = fmaf(wv.y, xa.y, hA1);
                hA0 = fmaf(wv.z, xa.z, hA0); hA1 = fmaf(wv.w, xa.w, hA1);
                hB0 = fmaf(wv.x, xb.x, hB0); hB1 = fmaf(wv.y, xb.y, hB1);
                hB0 = fmaf(wv.z, xb.z, hB0); hB1 = fmaf(wv.w, xb.w, hB1);
            }
            float ssA = wave_sum(ldA ? ssp : 0.f);
            float ssB = wave_sum(ldB ? ssp : 0.f);
            float zA  = wave_sum(fmaxf(hA0 + hA1, 0.f) * w2j) + b2v;
            float zB  = wave_sum(fmaxf(hB0 + hB1, 0.f) * w2j) + b2v;
            acc += coefA*ssA - 1.f/(1.f + expf(-zA))
                 + coefB*ssB - 1.f/(1.f + expf(-zB));
        }
        if (lane == 0) red[wid] = acc;
        __syncthreads();
        if (threadIdx.x == 0)
            partialQ[blockIdx.x - PREBLKS] = red[0]+red[1]+red[2]+red[3];
    }
}

// ---------- kernel 3: one wave per (b,t); two-phase scan, no per-step cross-lane ops ----------
__global__ __launch_bounds__(64) void k_main(
    const float* __restrict__ A, const float* __restrict__ rda0,
    const float* __restrict__ ra0c, const float* __restrict__ kesc,
    const float* __restrict__ kes0, const float* __restrict__ rda0self,
    const int* __restrict__ item_ids, const int* __restrict__ itemset,
    float* __restrict__ partial)
{
    __shared__ float Als[Kk*51];     // A[b], padded 51 (odd stride -> conflict-free columns)
    __shared__ float Cum[Kk*51];     // prefix sums, same layout
    __shared__ float2 js[Kk];        // per-j scalars {rda0_j, kesc_j}

    const int bt = blockIdx.x;
    const int b  = bt / Tt;
    const int lane = threadIdx.x;

    for (int i = lane; i < Kk*Kk; i += 64) {
        int k = i / Kk;
        Als[k*51 + (i - k*Kk)] = A[(long)b*Kk*Kk + i];
    }

    const int  myitem = item_ids[bt];
    const bool valid  = lane < Kk;
    const int  cj     = valid ? itemset[b*Kk+lane] : -1;
    const bool mj     = valid && (cj != myitem);
    const unsigned long long mask = __ballot(mj);

    const float rj_own = valid ? rda0[(long)bt*Kk+lane] : 0.f;
    const float kc_own = valid ? kesc[b*Kk+lane] : 0.f;
    const float raj    = valid ? ra0c[(long)bt*Kk+lane] : 0.f;
    if (valid) js[lane] = make_float2(rj_own, kc_own);

    const unsigned mlo = (unsigned)mask, mhi = (unsigned)(mask >> 32);
    const int below = __builtin_amdgcn_mbcnt_hi(mhi, __builtin_amdgcn_mbcnt_lo(mlo, 0));
    const float len    = 1.f + (float)below + (mj ? 1.f : 0.f);
    const float invden = 1.f / ((len + 1.f) * (float)Ee);
    const float invlen = 1.f / ((float)Ee * len);

    float pv = mj ? raj : 0.f;
    #pragma unroll
    for (int off = 1; off <= 32; off <<= 1) {
        float u = __shfl_up(pv, off, 64);
        if (lane >= off) pv += u;
    }
    const float cumra  = pv;
    const float r0self = rda0self[bt];
    const float k0     = kes0[bt];

    asm volatile("s_waitcnt lgkmcnt(0)" ::: "memory");

    if (valid) {
        float cum = 0.f;
        #pragma unroll 5
        for (int k = 0; k < Kk; ++k) {
            float mfk = ((mask >> k) & 1ull) ? 1.0f : 0.0f;
            cum = fmaf(mfk, Als[k*51 + lane], cum);
            Cum[k*51 + lane] = cum;
        }
    }
    asm volatile("s_waitcnt lgkmcnt(0)" ::: "memory");

    const int lc = valid ? lane : (Kk-1);
    float max0 = -3e38f, maxc = -3e38f, diag = 0.f;
    #pragma unroll 2
    for (int j = 0; j < Kk; ++j) {
        float c = Cum[lc*51 + j];
        if (j == lane) diag = c;
        if ((mask >> j) & 1ull) {
            float  a  = Als[lc*51 + j];
            float2 sj = js[j];
            float v0 = fmaf(c + 2.f*sj.x, invden, sj.y);
            float vc = fmaf(a - sj.x,    invden, v0);
            if (lane < j) { max0 = fmaxf(max0, v0); maxc = fmaxf(maxc, vc); }
        }
    }

    float look0 = fmaxf(0.f, max0);
    float lookc = fmaxf(0.f, maxc);
    float Kes0 = k0     + fmaf(r0self + cumra, invlen, look0);
    float KesC = kc_own + fmaf(rj_own + diag,  invlen, lookc);
    float x = Kes0 - KesC;
    float term = (x >= 0.f) ? -log1pf(expf(-x)) : (x - log1pf(expf(x)));
    float contrib = mj ? term : 0.f;
    float s = wave_sum(contrib);
    if (lane == 0) partial[bt] = s;
}

// ---------- kernel 4: deterministic final reduce ----------
__global__ __launch_bounds__(256) void k_final(
    const float* __restrict__ p1, int n1,
    const float* __restrict__ p3, int n3,
    float* __restrict__ out)
{
    __shared__ double sh[256];
    double s = 0.0;
    for (int i = threadIdx.x; i < n1; i += 256) s += (double)p1[i];
    for (int i = threadIdx.x; i < n3; i += 256) s += (double)p3[i];
    sh[threadIdx.x] = s;
    __syncthreads();
    for (int m = 128; m >= 1; m >>= 1) {
        if (threadIdx.x < m) sh[threadIdx.x] += sh[threadIdx.x + m];
        __syncthreads();
    }
    if (threadIdx.x == 0) out[0] = (float)sh[0];
}

// ---------- launch ----------
extern "C" void kernel_launch(void* const* d_in, const int* in_sizes, int n_in,
                              void* d_out, int out_size, void* d_ws, size_t ws_size,
                              hipStream_t stream) {
    const float* alpha      = (const float*)d_in[0];
    const float* rho        = (const float*)d_in[1];
    const float* lam        = (const float*)d_in[2];
    const float* beta       = (const float*)d_in[3];
    const float* mu_tab     = (const float*)d_in[4];
    const float* theta      = (const float*)d_in[5];
    const float* gamma_     = (const float*)d_in[6];
    const float* w1         = (const float*)d_in[7];
    const float* b1         = (const float*)d_in[8];
    const float* w2         = (const float*)d_in[9];
    const float* b2         = (const float*)d_in[10];
    const float* sigma_list = (const float*)d_in[11];
    // d_in[12] = mu_list (all zeros; folded out)
    const float* prices      = (const float*)d_in[13];
    const float* price_table = (const float*)d_in[14];
    const int*   item_ids    = (const int*)d_in[15];
    const int*   itemset     = (const int*)d_in[16];
    const int*   userid      = (const int*)d_in[17];

    float* ws = (float*)d_ws;
    const size_t offA    = 0;                         // B*K*K
    const size_t offRDA  = offA   + (size_t)Bb*Kk*Kk; // B*T*K
    const size_t offRA0C = offRDA + (size_t)Bb*Tt*Kk; // B*T*K
    const size_t offKESC = offRA0C+ (size_t)Bb*Tt*Kk; // B*K
    const size_t offKES0 = offKESC+ (size_t)Bb*Kk;    // B*T
    const size_t offSELF = offKES0+ (size_t)Bb*Tt;    // B*T
    const size_t offP1   = offSELF+ (size_t)Bb*Tt;    // QBLKS
    const size_t offP3   = offP1  + QBLKS;            // NB3

    const int NB3 = Bb * Tt;   // 1280

    k_fused1<<<PREBLKS + QBLKS, 256, 0, stream>>>(
        alpha, rho, lam, beta, mu_tab, theta, gamma_,
        w1, b1, w2, b2, sigma_list, prices, price_table,
        item_ids, itemset, userid,
        ws + offA, ws + offRDA, ws + offRA0C,
        ws + offKESC, ws + offKES0, ws + offSELF,
        ws + offP1);
    k_main<<<NB3, 64, 0, stream>>>(ws + offA, ws + offRDA, ws + offRA0C,
                                   ws + offKESC, ws + offKES0, ws + offSELF,
                                   item_ids, itemset, ws + offP3);
    k_final<<<1, 256, 0, stream>>>(ws + offP1, QBLKS, ws + offP3, NB3, (float*)d_out);
}

// Round 5
// 45.544 us; speedup vs baseline: 3.0701x; 1.1553x over previous
//
#include <hip/hip_runtime.h>
#include <math.h>

#define Ee 100
#define Hh 64
#define Bb 64
#define Tt 20
#define Kk 50
#define NROWS (5*Bb*Kk + 2*Bb)   // 16128
#define NPAIRS (NROWS/2)         // 8064
#define PREBLKS 256
#define QBLKS   256

// ---------- helpers ----------
__device__ __forceinline__ float wave_sum(float v) {
    #pragma unroll
    for (int m = 32; m >= 1; m >>= 1) v += __shfl_xor(v, m, 64);
    return v;
}

// ---------- kernel A: fused {Q-network+prior} and {per-b precompute} ----------
// blocks [0,256): pre role (4 blocks per b). blocks [256,512): qprior role.
__global__ __launch_bounds__(256) void k_fused1(
    const float* __restrict__ alpha, const float* __restrict__ rho,
    const float* __restrict__ lam,   const float* __restrict__ beta,
    const float* __restrict__ mu_tab,const float* __restrict__ theta,
    const float* __restrict__ gamma_,const float* __restrict__ w1,
    const float* __restrict__ b1,    const float* __restrict__ w2,
    const float* __restrict__ b2,    const float* __restrict__ sigma_list,
    const float* __restrict__ prices,const float* __restrict__ price_table,
    const int* __restrict__ item_ids,const int* __restrict__ itemset,
    const int* __restrict__ userid,
    float* __restrict__ A, float* __restrict__ rda0, float* __restrict__ ra0c,
    float* __restrict__ kesc, float* __restrict__ kes0, float* __restrict__ rda0self,
    float* __restrict__ partialQ)
{
    __shared__ float buf[11312];
    const int lane = threadIdx.x & 63;
    const int wid  = threadIdx.x >> 6;

    if (blockIdx.x < PREBLKS) {
        // ================= pre role =================
        float* ac  = buf;            // Kk*101
        float* rc  = buf + 5050;     // Kk*101
        float* a0s = buf + 10100;    // 5*101
        float* r0s = buf + 10605;    // 5*101
        float* th  = buf + 11110;    // Ee
        float* ga  = buf + 11210;    // Ee

        const int b = blockIdx.x >> 2, q = blockIdx.x & 3;
        const int kcnt = (q < 2) ? 13 : 12;
        const int kbeg = q*12 + ((q < 2) ? q : 2);
        const int tbeg = q*5;
        const long uid = userid[b];

        for (int i = threadIdx.x; i < Ee; i += 256) {
            th[i] = theta[uid*Ee+i];
            ga[i] = gamma_[uid*Ee+i];
        }
        for (int i = threadIdx.x; i < Kk*Ee; i += 256) {
            int k = i/Ee, e = i - k*Ee;
            long idx = itemset[b*Kk+k];
            ac[k*101+e] = alpha[idx*Ee+e];
            rc[k*101+e] = rho[idx*Ee+e];
        }
        for (int i = threadIdx.x; i < 5*Ee; i += 256) {
            int tl = i/Ee, e = i - tl*Ee;
            long idx = item_ids[b*Tt + tbeg + tl];
            a0s[tl*101+e] = alpha[idx*Ee+e];
            r0s[tl*101+e] = rho[idx*Ee+e];
        }
        __syncthreads();

        for (int p = threadIdx.x; p < kcnt*Kk; p += 256) {
            int k = kbeg + p/Kk, j = p - (p/Kk)*Kk;
            float s = 0.f;
            #pragma unroll 4
            for (int e = 0; e < Ee; ++e) s = fmaf(ac[k*101+e], rc[j*101+e], s);
            A[((long)b*Kk+k)*Kk+j] = s;
        }
        for (int p = threadIdx.x; p < 5*Kk; p += 256) {
            int tl = p/Kk, j = p - tl*Kk;
            float s1 = 0.f, s2 = 0.f;
            #pragma unroll 4
            for (int e = 0; e < Ee; ++e) {
                s1 = fmaf(rc[j*101+e], a0s[tl*101+e], s1);
                s2 = fmaf(r0s[tl*101+e], ac[j*101+e], s2);
            }
            int t = tbeg + tl;
            rda0[((long)b*Tt+t)*Kk+j] = s1;
            ra0c[((long)b*Tt+t)*Kk+j] = s2;
        }
        for (int task = wid; task < 5 + kcnt; task += 4) {
            if (task < 5) {
                int tl = task, t = tbeg + tl;
                long idx = item_ids[b*Tt+t];
                float s=0.f, ml=0.f, mtha=0.f, mgb=0.f;
                if (lane < Kk) {
                    #pragma unroll
                    for (int u = 0; u < 2; ++u) {
                        int e = lane + u*Kk;
                        float a0v = a0s[tl*101+e], r0v = r0s[tl*101+e];
                        s    = fmaf(r0v, a0v, s);
                        ml  += lam[idx*Ee+e];
                        mtha = fmaf(th[e], a0v, mtha);
                        mgb  = fmaf(ga[e], beta[idx*Ee+e], mgb);
                    }
                }
                s = wave_sum(s); ml = wave_sum(ml); mtha = wave_sum(mtha); mgb = wave_sum(mgb);
                if (lane == 0) {
                    rda0self[b*Tt+t] = s;
                    kes0[b*Tt+t] = 0.01f*ml + 0.01f*mtha - 0.01f*mgb*logf(prices[b*Tt+t]);
                }
            } else {
                int k = kbeg + (task - 5);
                long idx = itemset[b*Kk+k];
                float ml=0.f, mtha=0.f, mgb=0.f;
                if (lane < Kk) {
                    #pragma unroll
                    for (int u = 0; u < 2; ++u) {
                        int e = lane + u*Kk;
                        ml  += lam[idx*Ee+e];
                        mtha = fmaf(th[e], ac[k*101+e], mtha);
                        mgb  = fmaf(ga[e], beta[idx*Ee+e], mgb);
                    }
                }
                ml = wave_sum(ml); mtha = wave_sum(mtha); mgb = wave_sum(mgb);
                if (lane == 0)
                    kesc[b*Kk+k] = 0.01f*ml + 0.01f*mtha - 0.01f*mgb*logf(price_table[idx]);
            }
        }
    } else {
        // ================= qprior role =================
        // Segment boundaries (3200s, 16000, 16064) are all even -> rows (2p,2p+1)
        // always share one segment: one table pointer + one coef per pair.
        float* w1s = buf;                  // 6400 floats, row-major [64][100]
        float* xsA = buf + 6400 + wid*208; // 104 per row, 2 rows per wave
        float* xsB = xsA + 104;
        float* red = buf + 7236;           // 4

        for (int i = threadIdx.x; i < Hh*Ee; i += 256) w1s[i] = w1[i];
        __syncthreads();

        const float w2j = w2[lane];
        const float b1j = b1[lane];
        const float b2v = b2[0];

        const int wave = (blockIdx.x - PREBLKS)*4 + wid;
        const bool ldA = (lane < 25);
        const bool ldB = (lane >= 32) && (lane < 57);
        const int  lq  = ldA ? (lane<<2) : ((lane-32)<<2);

        // pair descriptor (straight-line, registers only)
        #define PAIR_DESC(p, tab, coef, iA, iB)                                   \
        {                                                                         \
            if ((p) < 8000) {                                                     \
                int seg = (p) / 1600;                                             \
                int r2  = 2*(p) - seg*3200;                                       \
                iA = itemset[r2]; iB = itemset[r2+1];                             \
                tab = (seg==0)?alpha:(seg==1)?rho:(seg==2)?lam:(seg==3)?beta:mu_tab; \
                coef = -0.5f / sigma_list[seg];                                   \
            } else if ((p) < 8032) {                                              \
                int r2 = 2*(p) - 16000;                                           \
                iA = userid[r2]; iB = userid[r2+1];                               \
                tab = theta; coef = -0.5f / sigma_list[5];                        \
            } else {                                                              \
                int r2 = 2*(p) - 16064;                                           \
                iA = userid[r2]; iB = userid[r2+1];                               \
                tab = gamma_; coef = -0.5f / sigma_list[6];                       \
            }                                                                     \
        }

        float acc = 0.f;
        const float* tab; float coef; int iA, iB;
        float4 cur = make_float4(0.f,0.f,0.f,0.f);
        float  curcoef = 0.f;
        if (wave < NPAIRS) {
            PAIR_DESC(wave, tab, coef, iA, iB);
            curcoef = coef;
            const float* xp = tab + (long)(ldA ? iA : iB)*Ee;
            if (ldA || ldB) cur = *(const float4*)(xp + lq);
        }
        for (int p = wave; p < NPAIRS; p += QBLKS*4) {
            // stage current pair into LDS
            if (ldA)      *(float4*)(&xsA[lq]) = cur;
            else if (ldB) *(float4*)(&xsB[lq]) = cur;
            float ssp = cur.x*cur.x + cur.y*cur.y + cur.z*cur.z + cur.w*cur.w;
            float cc = curcoef;

            // prefetch next pair (vmcnt stays in flight under the h-loop)
            float4 nxt = make_float4(0.f,0.f,0.f,0.f);
            int pn = p + QBLKS*4;
            if (pn < NPAIRS) {
                PAIR_DESC(pn, tab, coef, iA, iB);
                curcoef = coef;
                const float* xp = tab + (long)(ldA ? iA : iB)*Ee;
                if (ldA || ldB) nxt = *(const float4*)(xp + lq);
            }
            asm volatile("s_waitcnt lgkmcnt(0)" ::: "memory");  // LDS stores visible (in-wave)

            float hA0 = b1j, hA1 = 0.f, hB0 = b1j, hB1 = 0.f;
            #pragma unroll
            for (int i = 0; i < Ee/4; ++i) {
                float4 wv = *(const float4*)(&w1s[lane*Ee + i*4]);  // own row, b128
                float4 xa = *(const float4*)(&xsA[i*4]);            // broadcast
                float4 xb = *(const float4*)(&xsB[i*4]);            // broadcast
                hA0 = fmaf(wv.x, xa.x, hA0); hA1 = fmaf(wv.y, xa.y, hA1);
                hA0 = fmaf(wv.z, xa.z, hA0); hA1 = fmaf(wv.w, xa.w, hA1);
                hB0 = fmaf(wv.x, xb.x, hB0); hB1 = fmaf(wv.y, xb.y, hB1);
                hB0 = fmaf(wv.z, xb.z, hB0); hB1 = fmaf(wv.w, xb.w, hB1);
            }
            float ssA = wave_sum(ldA ? ssp : 0.f);
            float ssB = wave_sum(ldB ? ssp : 0.f);
            float zA  = wave_sum(fmaxf(hA0 + hA1, 0.f) * w2j) + b2v;
            float zB  = wave_sum(fmaxf(hB0 + hB1, 0.f) * w2j) + b2v;
            acc += cc*(ssA + ssB) - 1.f/(1.f + expf(-zA)) - 1.f/(1.f + expf(-zB));
            cur = nxt;
        }
        #undef PAIR_DESC
        if (lane == 0) red[wid] = acc;
        __syncthreads();
        if (threadIdx.x == 0)
            partialQ[blockIdx.x - PREBLKS] = red[0]+red[1]+red[2]+red[3];
    }
}

// ---------- kernel 3: one wave per (b,t); two-phase scan ----------
__global__ __launch_bounds__(64) void k_main(
    const float* __restrict__ A, const float* __restrict__ rda0,
    const float* __restrict__ ra0c, const float* __restrict__ kesc,
    const float* __restrict__ kes0, const float* __restrict__ rda0self,
    const int* __restrict__ item_ids, const int* __restrict__ itemset,
    float* __restrict__ partial)
{
    __shared__ float Als[Kk*51];
    __shared__ float Cum[Kk*51];
    __shared__ float2 js[Kk];

    const int bt = blockIdx.x;
    const int b  = bt / Tt;
    const int lane = threadIdx.x;

    for (int i = lane; i < Kk*Kk; i += 64) {
        int k = i / Kk;
        Als[k*51 + (i - k*Kk)] = A[(long)b*Kk*Kk + i];
    }

    const int  myitem = item_ids[bt];
    const bool valid  = lane < Kk;
    const int  cj     = valid ? itemset[b*Kk+lane] : -1;
    const bool mj     = valid && (cj != myitem);
    const unsigned long long mask = __ballot(mj);

    const float rj_own = valid ? rda0[(long)bt*Kk+lane] : 0.f;
    const float kc_own = valid ? kesc[b*Kk+lane] : 0.f;
    const float raj    = valid ? ra0c[(long)bt*Kk+lane] : 0.f;
    if (valid) js[lane] = make_float2(rj_own, kc_own);

    const unsigned mlo = (unsigned)mask, mhi = (unsigned)(mask >> 32);
    const int below = __builtin_amdgcn_mbcnt_hi(mhi, __builtin_amdgcn_mbcnt_lo(mlo, 0));
    const float len    = 1.f + (float)below + (mj ? 1.f : 0.f);
    const float invden = 1.f / ((len + 1.f) * (float)Ee);
    const float invlen = 1.f / ((float)Ee * len);

    float pv = mj ? raj : 0.f;
    #pragma unroll
    for (int off = 1; off <= 32; off <<= 1) {
        float u = __shfl_up(pv, off, 64);
        if (lane >= off) pv += u;
    }
    const float cumra  = pv;
    const float r0self = rda0self[bt];
    const float k0     = kes0[bt];

    asm volatile("s_waitcnt lgkmcnt(0)" ::: "memory");

    if (valid) {
        float cum = 0.f;
        #pragma unroll 5
        for (int k = 0; k < Kk; ++k) {
            float mfk = ((mask >> k) & 1ull) ? 1.0f : 0.0f;
            cum = fmaf(mfk, Als[k*51 + lane], cum);
            Cum[k*51 + lane] = cum;
        }
    }
    asm volatile("s_waitcnt lgkmcnt(0)" ::: "memory");

    const int lc = valid ? lane : (Kk-1);
    float max0 = -3e38f, maxc = -3e38f, diag = 0.f;
    #pragma unroll 2
    for (int j = 0; j < Kk; ++j) {
        float c = Cum[lc*51 + j];
        if (j == lane) diag = c;
        if ((mask >> j) & 1ull) {
            float  a  = Als[lc*51 + j];
            float2 sj = js[j];
            float v0 = fmaf(c + 2.f*sj.x, invden, sj.y);
            float vc = fmaf(a - sj.x,    invden, v0);
            if (lane < j) { max0 = fmaxf(max0, v0); maxc = fmaxf(maxc, vc); }
        }
    }

    float look0 = fmaxf(0.f, max0);
    float lookc = fmaxf(0.f, maxc);
    float Kes0 = k0     + fmaf(r0self + cumra, invlen, look0);
    float KesC = kc_own + fmaf(rj_own + diag,  invlen, lookc);
    float x = Kes0 - KesC;
    float term = (x >= 0.f) ? -log1pf(expf(-x)) : (x - log1pf(expf(x)));
    float contrib = mj ? term : 0.f;
    float s = wave_sum(contrib);
    if (lane == 0) partial[bt] = s;
}

// ---------- kernel 4: deterministic final reduce ----------
__global__ __launch_bounds__(256) void k_final(
    const float* __restrict__ p1, int n1,
    const float* __restrict__ p3, int n3,
    float* __restrict__ out)
{
    __shared__ double sh[256];
    double s = 0.0;
    for (int i = threadIdx.x; i < n1; i += 256) s += (double)p1[i];
    for (int i = threadIdx.x; i < n3; i += 256) s += (double)p3[i];
    sh[threadIdx.x] = s;
    __syncthreads();
    for (int m = 128; m >= 1; m >>= 1) {
        if (threadIdx.x < m) sh[threadIdx.x] += sh[threadIdx.x + m];
        __syncthreads();
    }
    if (threadIdx.x == 0) out[0] = (float)sh[0];
}

// ---------- launch ----------
extern "C" void kernel_launch(void* const* d_in, const int* in_sizes, int n_in,
                              void* d_out, int out_size, void* d_ws, size_t ws_size,
                              hipStream_t stream) {
    const float* alpha      = (const float*)d_in[0];
    const float* rho        = (const float*)d_in[1];
    const float* lam        = (const float*)d_in[2];
    const float* beta       = (const float*)d_in[3];
    const float* mu_tab     = (const float*)d_in[4];
    const float* theta      = (const float*)d_in[5];
    const float* gamma_     = (const float*)d_in[6];
    const float* w1         = (const float*)d_in[7];
    const float* b1         = (const float*)d_in[8];
    const float* w2         = (const float*)d_in[9];
    const float* b2         = (const float*)d_in[10];
    const float* sigma_list = (const float*)d_in[11];
    // d_in[12] = mu_list (all zeros; folded out)
    const float* prices      = (const float*)d_in[13];
    const float* price_table = (const float*)d_in[14];
    const int*   item_ids    = (const int*)d_in[15];
    const int*   itemset     = (const int*)d_in[16];
    const int*   userid      = (const int*)d_in[17];

    float* ws = (float*)d_ws;
    const size_t offA    = 0;                         // B*K*K
    const size_t offRDA  = offA   + (size_t)Bb*Kk*Kk; // B*T*K
    const size_t offRA0C = offRDA + (size_t)Bb*Tt*Kk; // B*T*K
    const size_t offKESC = offRA0C+ (size_t)Bb*Tt*Kk; // B*K
    const size_t offKES0 = offKESC+ (size_t)Bb*Kk;    // B*T
    const size_t offSELF = offKES0+ (size_t)Bb*Tt;    // B*T
    const size_t offP1   = offSELF+ (size_t)Bb*Tt;    // QBLKS
    const size_t offP3   = offP1  + QBLKS;            // NB3

    const int NB3 = Bb * Tt;   // 1280

    k_fused1<<<PREBLKS + QBLKS, 256, 0, stream>>>(
        alpha, rho, lam, beta, mu_tab, theta, gamma_,
        w1, b1, w2, b2, sigma_list, prices, price_table,
        item_ids, itemset, userid,
        ws + offA, ws + offRDA, ws + offRA0C,
        ws + offKESC, ws + offKES0, ws + offSELF,
        ws + offP1);
    k_main<<<NB3, 64, 0, stream>>>(ws + offA, ws + offRDA, ws + offRA0C,
                                   ws + offKESC, ws + offKES0, ws + offSELF,
                                   item_ids, itemset, ws + offP3);
    k_final<<<1, 256, 0, stream>>>(ws + offP1, QBLKS, ws + offP3, NB3, (float*)d_out);
}